// Round 1
// 1275.627 us; speedup vs baseline: 1.9632x; 1.9632x over previous
//
#include <hip/hip_runtime.h>

#define B_    512
#define T_    256
#define D_    64
#define H_    8
#define E_    8
#define HID_  2048
#define EPS_  1e-5f
#define SCALE_ 0.3535533905932738f  // 1/sqrt(8)

// ---------------- Kernel A: per-(b,h) QKV + causal online-softmax attention ----------------
__global__ __launch_bounds__(256) void attn_k(
    const float* __restrict__ x,
    const float* __restrict__ Wq, const float* __restrict__ bq,
    const float* __restrict__ Wk, const float* __restrict__ bk,
    const float* __restrict__ Wv, const float* __restrict__ bv,
    float* __restrict__ o_ws)
{
  __shared__ __align__(16) float xs[64][68];            // 64-token x chunk, pad 68
  __shared__ __align__(16) float qs[256][8], ks[256][8], vs[256][8];
  __shared__ __align__(16) float wqs[512], wks[512], wvs[512];  // [d][e] flat
  __shared__ float bqs[8], bks[8], bvs[8];

  const int tid = threadIdx.x;
  const int b = blockIdx.x >> 3, h = blockIdx.x & 7;

  // stage per-head weights (64x8 each)
  for (int i = tid; i < 512; i += 256) {
    wqs[i] = Wq[h * 512 + i];
    wks[i] = Wk[h * 512 + i];
    wvs[i] = Wv[h * 512 + i];
  }
  if (tid < 8) {
    bqs[tid] = bq[h * 8 + tid];
    bks[tid] = bk[h * 8 + tid];
    bvs[tid] = bv[h * 8 + tid];
  }

  // QKV in 4 chunks of 64 tokens
  const int e = tid & 7, tg = tid >> 3;
  for (int ch = 0; ch < 4; ++ch) {
    {
      const int r = tid >> 2, cq = tid & 3;
      const float* xrow = x + ((size_t)b * T_ + ch * 64 + r) * D_ + cq * 16;
      float* dst = &xs[r][cq * 16];
      #pragma unroll
      for (int c = 0; c < 4; ++c)
        *(float4*)&dst[c * 4] = *(const float4*)&xrow[c * 4];
    }
    __syncthreads();
    #pragma unroll
    for (int i = 0; i < 2; ++i) {
      const int tl = tg + 32 * i, t = ch * 64 + tl;
      float aq = bqs[e], ak = bks[e], av = bvs[e];
      #pragma unroll
      for (int c = 0; c < 16; ++c) {
        float4 xv = *(const float4*)&xs[tl][c * 4];
        const int d = c * 4;
        aq += xv.x * wqs[(d + 0) * 8 + e] + xv.y * wqs[(d + 1) * 8 + e]
            + xv.z * wqs[(d + 2) * 8 + e] + xv.w * wqs[(d + 3) * 8 + e];
        ak += xv.x * wks[(d + 0) * 8 + e] + xv.y * wks[(d + 1) * 8 + e]
            + xv.z * wks[(d + 2) * 8 + e] + xv.w * wks[(d + 3) * 8 + e];
        av += xv.x * wvs[(d + 0) * 8 + e] + xv.y * wvs[(d + 1) * 8 + e]
            + xv.z * wvs[(d + 2) * 8 + e] + xv.w * wvs[(d + 3) * 8 + e];
      }
      qs[t][e] = aq * SCALE_;
      ks[t][e] = ak;
      vs[t][e] = av;
    }
    __syncthreads();
  }

  // attention: thread t = tid owns query row t, online softmax over s<=t
  {
    const int t = tid;
    float4 q0 = *(const float4*)&qs[t][0];
    float4 q1 = *(const float4*)&qs[t][4];
    float m = -INFINITY, l = 0.f;
    float o0 = 0, o1 = 0, o2 = 0, o3 = 0, o4 = 0, o5 = 0, o6 = 0, o7 = 0;
    for (int s = 0; s <= t; ++s) {     // all active lanes read same s -> LDS broadcast
      float4 ka = *(const float4*)&ks[s][0];
      float4 kb = *(const float4*)&ks[s][4];
      float sc = q0.x * ka.x + q0.y * ka.y + q0.z * ka.z + q0.w * ka.w
               + q1.x * kb.x + q1.y * kb.y + q1.z * kb.z + q1.w * kb.w;
      float mn = fmaxf(m, sc);
      float corr = __expf(m - mn);     // first iter: exp(-inf)=0
      float p = __expf(sc - mn);
      m = mn;
      l = l * corr + p;
      float4 va = *(const float4*)&vs[s][0];
      float4 vb = *(const float4*)&vs[s][4];
      o0 = o0 * corr + p * va.x;  o1 = o1 * corr + p * va.y;
      o2 = o2 * corr + p * va.z;  o3 = o3 * corr + p * va.w;
      o4 = o4 * corr + p * vb.x;  o5 = o5 * corr + p * vb.y;
      o6 = o6 * corr + p * vb.z;  o7 = o7 * corr + p * vb.w;
    }
    float inv = 1.f / l;
    float* orow = o_ws + ((size_t)b * T_ + t) * D_ + h * E_;
    float4 r0 = { o0 * inv, o1 * inv, o2 * inv, o3 * inv };
    float4 r1 = { o4 * inv, o5 * inv, o6 * inv, o7 * inv };
    *(float4*)&orow[0] = r0;
    *(float4*)&orow[4] = r1;
  }
}

// ---------------- Kernel B: output proj + residual + LN1 (32 tokens / WG) ----------------
__global__ __launch_bounds__(256) void proj_ln1_k(
    const float* __restrict__ x,
    const float* __restrict__ Wp, const float* __restrict__ bp,
    const float* __restrict__ g1, const float* __restrict__ be1,
    const float* __restrict__ o_ws, float* __restrict__ h_ws)
{
  __shared__ __align__(16) float os[32][68];   // pad 68
  __shared__ __align__(16) float wps[4096];    // Wp [i][d] flat
  const int tid = threadIdx.x;
  const size_t t0 = (size_t)blockIdx.x * 32;

  {
    const int t = tid >> 3, c = tid & 7;
    const float* orow = o_ws + (t0 + t) * D_ + c * 8;
    *(float4*)&os[t][c * 8 + 0] = *(const float4*)&orow[0];
    *(float4*)&os[t][c * 8 + 4] = *(const float4*)&orow[4];
  }
  #pragma unroll
  for (int c = 0; c < 4; ++c)
    ((float4*)wps)[tid + 256 * c] = ((const float4*)Wp)[tid + 256 * c];
  __syncthreads();

  const int t = tid >> 3, tl = tid & 7, d0 = tl * 8;
  float acc[8];
  {
    float4 b0 = *(const float4*)&bp[d0];
    float4 b1v = *(const float4*)&bp[d0 + 4];
    acc[0] = b0.x; acc[1] = b0.y; acc[2] = b0.z; acc[3] = b0.w;
    acc[4] = b1v.x; acc[5] = b1v.y; acc[6] = b1v.z; acc[7] = b1v.w;
  }
  for (int i = 0; i < 64; ++i) {
    float ov = os[t][i];
    const float* wr = &wps[i * 64 + d0];
    float4 w0 = *(const float4*)wr;
    float4 w1 = *(const float4*)(wr + 4);
    acc[0] += ov * w0.x; acc[1] += ov * w0.y; acc[2] += ov * w0.z; acc[3] += ov * w0.w;
    acc[4] += ov * w1.x; acc[5] += ov * w1.y; acc[6] += ov * w1.z; acc[7] += ov * w1.w;
  }
  // residual
  float r[8];
  {
    const float* xrow = x + (t0 + t) * D_ + d0;
    float4 x0 = *(const float4*)&xrow[0];
    float4 x1 = *(const float4*)&xrow[4];
    r[0] = x0.x + acc[0]; r[1] = x0.y + acc[1]; r[2] = x0.z + acc[2]; r[3] = x0.w + acc[3];
    r[4] = x1.x + acc[4]; r[5] = x1.y + acc[5]; r[6] = x1.z + acc[6]; r[7] = x1.w + acc[7];
  }
  float s1 = 0.f, s2 = 0.f;
  #pragma unroll
  for (int k = 0; k < 8; ++k) { s1 += r[k]; s2 += r[k] * r[k]; }
  #pragma unroll
  for (int mM = 1; mM < 8; mM <<= 1) {
    s1 += __shfl_xor(s1, mM, 8);
    s2 += __shfl_xor(s2, mM, 8);
  }
  float mu = s1 * (1.f / 64.f);
  float var = s2 * (1.f / 64.f) - mu * mu;
  float rstd = rsqrtf(var + EPS_);
  float4 g0 = *(const float4*)&g1[d0];
  float4 g1v = *(const float4*)&g1[d0 + 4];
  float4 e0 = *(const float4*)&be1[d0];
  float4 e1 = *(const float4*)&be1[d0 + 4];
  float4 h0, h1;
  h0.x = (r[0] - mu) * rstd * g0.x + e0.x;
  h0.y = (r[1] - mu) * rstd * g0.y + e0.y;
  h0.z = (r[2] - mu) * rstd * g0.z + e0.z;
  h0.w = (r[3] - mu) * rstd * g0.w + e0.w;
  h1.x = (r[4] - mu) * rstd * g1v.x + e1.x;
  h1.y = (r[5] - mu) * rstd * g1v.y + e1.y;
  h1.z = (r[6] - mu) * rstd * g1v.z + e1.z;
  h1.w = (r[7] - mu) * rstd * g1v.w + e1.w;
  float* hrow = h_ws + (t0 + t) * D_ + d0;
  *(float4*)&hrow[0] = h0;
  *(float4*)&hrow[4] = h1;
}

// ---------------- Kernel C: FFN (64->2048->64) + residual + LN2 ----------------
// 32 tokens / WG. Register-blocked outer-product tiles:
//  P1: thread tile 8 tok x 4 cols; A from transposed ht[64][32] (wave-uniform
//      broadcast ds_read_b128 x2 per k), B = W1 row slice (1 coalesced dwordx4)
//      -> 32 FMA per 2 DS + 1 VMEM.
//  P2: 4-way K-split; thread tile 4 tok x 8 dims; per k4: 4 ds_read_b128 of hid
//      + 8 dwordx4 of W2 -> 128 FMA. Partials reduced through LDS at the end.
__global__ __launch_bounds__(256, 3) void ffn_ln2_k(
    const float* __restrict__ W1, const float* __restrict__ b1,
    const float* __restrict__ W2, const float* __restrict__ b2,
    const float* __restrict__ g2, const float* __restrict__ be2,
    const float* __restrict__ h_ws, float* __restrict__ out)
{
  __shared__ __align__(16) float ht[64][32];    // h transposed: ht[d][t]
  __shared__ __align__(16) float hid[32][260];  // hidden chunk; reused as red[4][32][64]
  const int tid = threadIdx.x;
  const size_t t0 = (size_t)blockIdx.x * 32;

  // stage h transposed (one-time; write conflicts negligible)
  {
    const int t = tid >> 3, ds = (tid & 7) * 8;
    const float* hrow = h_ws + (t0 + t) * D_ + ds;
    float4 a = *(const float4*)hrow;
    float4 b = *(const float4*)(hrow + 4);
    ht[ds + 0][t] = a.x; ht[ds + 1][t] = a.y; ht[ds + 2][t] = a.z; ht[ds + 3][t] = a.w;
    ht[ds + 4][t] = b.x; ht[ds + 5][t] = b.y; ht[ds + 6][t] = b.z; ht[ds + 7][t] = b.w;
  }

  const int mg  = tid >> 6;         // P1: token block (8 tokens), wave-uniform
  const int ng  = tid & 63;         // P1: col block (4 cols)
  const int kq  = tid >> 6;         // P2: K-quarter (wave-uniform)
  const int mg2 = (tid >> 3) & 7;   // P2: token block (4 tokens)
  const int ng2 = tid & 7;          // P2: dim block (8 dims)

  float acc2[4][8];                 // persistent GEMM2 partials (kq quarter)
  #pragma unroll
  for (int i = 0; i < 4; ++i)
    #pragma unroll
    for (int d = 0; d < 8; ++d) acc2[i][d] = 0.f;

  __syncthreads();

  for (int ch = 0; ch < 8; ++ch) {
    const int c0 = ch * 256;

    // ---- P1: hid[0..31][0..255] = relu(h @ W1[:, c0:c0+256] + b1)
    float acc1[8][4];
    {
      float4 bb = *(const float4*)&b1[c0 + ng * 4];
      #pragma unroll
      for (int i = 0; i < 8; ++i) {
        acc1[i][0] = bb.x; acc1[i][1] = bb.y; acc1[i][2] = bb.z; acc1[i][3] = bb.w;
      }
    }
    const float* w1p = W1 + c0 + ng * 4;
    #pragma unroll 4
    for (int k = 0; k < 64; ++k) {
      float4 w  = *(const float4*)&w1p[(size_t)k * HID_];
      float4 a0 = *(const float4*)&ht[k][mg * 8];
      float4 a1 = *(const float4*)&ht[k][mg * 8 + 4];
      float am[8], wv[4];
      *(float4*)&am[0] = a0; *(float4*)&am[4] = a1;
      *(float4*)&wv[0] = w;
      #pragma unroll
      for (int i = 0; i < 8; ++i)
        #pragma unroll
        for (int c = 0; c < 4; ++c)
          acc1[i][c] += am[i] * wv[c];
    }
    #pragma unroll
    for (int i = 0; i < 8; ++i) {
      float4 r;
      r.x = fmaxf(acc1[i][0], 0.f); r.y = fmaxf(acc1[i][1], 0.f);
      r.z = fmaxf(acc1[i][2], 0.f); r.w = fmaxf(acc1[i][3], 0.f);
      *(float4*)&hid[mg * 8 + i][ng * 4] = r;   // full-row coalesced LDS write
    }
    __syncthreads();

    // ---- P2: acc2 += hid @ W2[c0+kq*64 .. +64, :] (this thread's K quarter)
    const float* w2p = W2 + ((size_t)c0 + (size_t)kq * 64) * D_ + ng2 * 8;
    #pragma unroll 2
    for (int kk = 0; kk < 64; kk += 4) {
      const int j = kq * 64 + kk;
      float hv[4][4];
      #pragma unroll
      for (int i = 0; i < 4; ++i)
        *(float4*)&hv[i][0] = *(const float4*)&hid[mg2 * 4 + i][j];
      const float* wp = w2p + (size_t)kk * D_;
      #pragma unroll
      for (int u = 0; u < 4; ++u) {
        float4 w0  = *(const float4*)&wp[u * D_];
        float4 w1v = *(const float4*)&wp[u * D_ + 4];
        #pragma unroll
        for (int i = 0; i < 4; ++i) {
          const float h = hv[i][u];
          acc2[i][0] += h * w0.x;  acc2[i][1] += h * w0.y;
          acc2[i][2] += h * w0.z;  acc2[i][3] += h * w0.w;
          acc2[i][4] += h * w1v.x; acc2[i][5] += h * w1v.y;
          acc2[i][6] += h * w1v.z; acc2[i][7] += h * w1v.w;
        }
      }
    }
    __syncthreads();
  }

  // ---- kq reduction through LDS (reuse hid region: red[4][32][64] = 8192 floats)
  {
    float* red = &hid[0][0];
    #pragma unroll
    for (int i = 0; i < 4; ++i) {
      float* dst = red + (size_t)(kq * 32 + mg2 * 4 + i) * 64 + ng2 * 8;
      float4 r0 = { acc2[i][0], acc2[i][1], acc2[i][2], acc2[i][3] };
      float4 r1 = { acc2[i][4], acc2[i][5], acc2[i][6], acc2[i][7] };
      *(float4*)&dst[0] = r0;
      *(float4*)&dst[4] = r1;
    }
  }
  __syncthreads();

  // ---- final: sum quarters + b2 + residual(h from ht) + LN2 + store
  {
    const float* red = &hid[0][0];
    const int tf = tid >> 3, df = (tid & 7) * 8;
    float r[8];
    {
      float4 s0 = *(const float4*)&red[(size_t)tf * 64 + df];
      float4 s1v = *(const float4*)&red[(size_t)tf * 64 + df + 4];
      #pragma unroll
      for (int q = 1; q < 4; ++q) {
        float4 a0 = *(const float4*)&red[((size_t)q * 32 + tf) * 64 + df];
        float4 a1 = *(const float4*)&red[((size_t)q * 32 + tf) * 64 + df + 4];
        s0.x += a0.x; s0.y += a0.y; s0.z += a0.z; s0.w += a0.w;
        s1v.x += a1.x; s1v.y += a1.y; s1v.z += a1.z; s1v.w += a1.w;
      }
      float4 b0 = *(const float4*)&b2[df];
      float4 b1v = *(const float4*)&b2[df + 4];
      r[0] = s0.x + b0.x + ht[df + 0][tf];
      r[1] = s0.y + b0.y + ht[df + 1][tf];
      r[2] = s0.z + b0.z + ht[df + 2][tf];
      r[3] = s0.w + b0.w + ht[df + 3][tf];
      r[4] = s1v.x + b1v.x + ht[df + 4][tf];
      r[5] = s1v.y + b1v.y + ht[df + 5][tf];
      r[6] = s1v.z + b1v.z + ht[df + 6][tf];
      r[7] = s1v.w + b1v.w + ht[df + 7][tf];
    }
    float s1 = 0.f, s2 = 0.f;
    #pragma unroll
    for (int k = 0; k < 8; ++k) { s1 += r[k]; s2 += r[k] * r[k]; }
    #pragma unroll
    for (int mM = 1; mM < 8; mM <<= 1) {
      s1 += __shfl_xor(s1, mM, 8);
      s2 += __shfl_xor(s2, mM, 8);
    }
    float mu = s1 * (1.f / 64.f);
    float var = s2 * (1.f / 64.f) - mu * mu;
    float rstd = rsqrtf(var + EPS_);
    float4 g0 = *(const float4*)&g2[df];
    float4 g1v = *(const float4*)&g2[df + 4];
    float4 e0 = *(const float4*)&be2[df];
    float4 e1 = *(const float4*)&be2[df + 4];
    float4 o0, o1;
    o0.x = (r[0] - mu) * rstd * g0.x + e0.x;
    o0.y = (r[1] - mu) * rstd * g0.y + e0.y;
    o0.z = (r[2] - mu) * rstd * g0.z + e0.z;
    o0.w = (r[3] - mu) * rstd * g0.w + e0.w;
    o1.x = (r[4] - mu) * rstd * g1v.x + e1.x;
    o1.y = (r[5] - mu) * rstd * g1v.y + e1.y;
    o1.z = (r[6] - mu) * rstd * g1v.z + e1.z;
    o1.w = (r[7] - mu) * rstd * g1v.w + e1.w;
    float* orow = out + (t0 + tf) * D_ + df;
    *(float4*)&orow[0] = o0;
    *(float4*)&orow[4] = o1;
  }
}

extern "C" void kernel_launch(void* const* d_in, const int* in_sizes, int n_in,
                              void* d_out, int out_size, void* d_ws, size_t ws_size,
                              hipStream_t stream) {
  const float* x   = (const float*)d_in[0];
  const float* Wq  = (const float*)d_in[1];
  const float* bq  = (const float*)d_in[2];
  const float* Wk  = (const float*)d_in[3];
  const float* bk  = (const float*)d_in[4];
  const float* Wv  = (const float*)d_in[5];
  const float* bv  = (const float*)d_in[6];
  const float* Wp  = (const float*)d_in[7];
  const float* bp  = (const float*)d_in[8];
  const float* g1  = (const float*)d_in[9];
  const float* be1 = (const float*)d_in[10];
  const float* W1  = (const float*)d_in[11];
  const float* b1  = (const float*)d_in[12];
  const float* W2  = (const float*)d_in[13];
  const float* b2  = (const float*)d_in[14];
  const float* g2  = (const float*)d_in[15];
  const float* be2 = (const float*)d_in[16];
  float* out = (float*)d_out;

  float* o_ws = (float*)d_ws;                            // [B*T*64] fp32 attn output (heads concat)
  float* h_ws = o_ws + (size_t)B_ * T_ * D_;             // [B*T*64] fp32 post-LN1

  attn_k<<<B_ * H_, 256, 0, stream>>>(x, Wq, bq, Wk, bk, Wv, bv, o_ws);
  proj_ln1_k<<<(B_ * T_) / 32, 256, 0, stream>>>(x, Wp, bp, g1, be1, o_ws, h_ws);
  ffn_ln2_k<<<(B_ * T_) / 32, 256, 0, stream>>>(W1, b1, W2, b2, g2, be2, h_ws, out);
}